// Round 4
// baseline (323.700 us; speedup 1.0000x reference)
//
#include <hip/hip_runtime.h>
#include <cmath>

typedef unsigned short u16;
typedef float floatx4 __attribute__((ext_vector_type(4)));
typedef short short8 __attribute__((ext_vector_type(8)));
typedef short short4v __attribute__((ext_vector_type(4)));
typedef __bf16 bf16x8 __attribute__((ext_vector_type(8)));

#define GLOBAL_AS __attribute__((address_space(1)))
#define LDS_AS __attribute__((address_space(3)))

#define S_LEN 2048
#define D_MODEL 2048
#define NH 16
#define NKV 4
#define DHEAD 128
#define SM_SCALE 0.08838834764831843f
#define K2 (SM_SCALE * 1.4426950408889634f) /* SM_SCALE * log2(e) */

__device__ __forceinline__ u16 f2bf(float f) {
    unsigned int u = __builtin_bit_cast(unsigned int, f);
    u += 0x7fffu + ((u >> 16) & 1u);
    return (u16)(u >> 16);
}
// cheap round-to-nearest (no tie-to-even): 2 VALU ops, used in the fa inner loop
__device__ __forceinline__ u16 f2bfr(float f) {
    unsigned int u = __builtin_bit_cast(unsigned int, f);
    return (u16)((u + 0x8000u) >> 16);
}
__device__ __forceinline__ float bf2f(u16 x) {
    unsigned int u = ((unsigned int)x) << 16;
    return __builtin_bit_cast(float, u);
}
__device__ __forceinline__ floatx4 zf4() {
    floatx4 z; z[0] = 0.f; z[1] = 0.f; z[2] = 0.f; z[3] = 0.f; return z;
}
__device__ __forceinline__ floatx4 mfma16(short8 a, short8 b, floatx4 c) {
    return __builtin_amdgcn_mfma_f32_16x16x32_bf16(
        __builtin_bit_cast(bf16x8, a), __builtin_bit_cast(bf16x8, b), c, 0, 0, 0);
}
// K=16 MFMA: A/B = 4 bf16 (2 VGPRs), k = quad*4 + j
__device__ __forceinline__ floatx4 mfma16k16(short4v a, short4v b, floatx4 c) {
    return __builtin_amdgcn_mfma_f32_16x16x16bf16_1k(a, b, c, 0, 0, 0);
}
__device__ __forceinline__ void async16(const u16* g, u16* l) {
    __builtin_amdgcn_global_load_lds((GLOBAL_AS void*)g, (LDS_AS void*)l, 16, 0, 0);
}

// ---------------- cast X fp32 -> bf16, plus rope tables (fused: one launch) ----------------
__global__ void cast_tables_kernel(const float4* __restrict__ in, ushort4* __restrict__ out,
                                   float* __restrict__ cs_tab, float* __restrict__ sn_tab) {
    int bid = blockIdx.x;
    if (bid < 8192) {
        int i = bid * 256 + threadIdx.x;
        float4 v = in[i];
        ushort4 o;
        o.x = f2bf(v.x); o.y = f2bf(v.y); o.z = f2bf(v.z); o.w = f2bf(v.w);
        out[i] = o;
    } else {
        int idx = (bid - 8192) * 256 + threadIdx.x;  // 2048*64
        int p = idx >> 6, jj = idx & 63;
        double e = (double)(2 * jj) / 128.0;
        double invf = pow(10000.0, -e);
        float arg = (float)p * (float)invf;  // match reference's fp32 angle
        cs_tab[idx] = (float)cos((double)arg);
        sn_tab[idx] = (float)sin((double)arg);
    }
}

// ---------------- transpose + cast all 4 weights in one launch ----------------
// in[R=2048][C] fp32 -> out[C][R] bf16.  blockIdx.x ranges select the matrix.
__global__ void transpose_all_kernel(const float* __restrict__ wq, const float* __restrict__ wk,
                                     const float* __restrict__ wv, const float* __restrict__ wo,
                                     u16* __restrict__ Wqkv, u16* __restrict__ Wo) {
    __shared__ float tile[32][33];
    int x = blockIdx.x;
    const float* in; u16* out; int C, bx;
    if (x < 64)      { in = wq; out = Wqkv;                     C = 2048; bx = x * 32; }
    else if (x < 80) { in = wk; out = Wqkv + (size_t)2048*2048; C = 512;  bx = (x - 64) * 32; }
    else if (x < 96) { in = wv; out = Wqkv + (size_t)2560*2048; C = 512;  bx = (x - 80) * 32; }
    else             { in = wo; out = Wo;                       C = 2048; bx = (x - 96) * 32; }
    const int R = 2048;
    int tx = threadIdx.x & 31, ty = threadIdx.x >> 5;
    int by = blockIdx.y * 32;  // over R
#pragma unroll
    for (int i = 0; i < 32; i += 8)
        tile[ty + i][tx] = in[(size_t)(by + ty + i) * C + bx + tx];
    __syncthreads();
#pragma unroll
    for (int i = 0; i < 32; i += 8)
        out[(size_t)(bx + ty + i) * R + by + tx] = f2bf(tile[tx][ty + i]);
}

// ---------------- apply RoPE in place on K only (Q rope is fused into fa) ----------------
__global__ void rope_k_kernel(u16* __restrict__ Kb, const int* __restrict__ pos,
                              const float4* __restrict__ cs_tab,
                              const float4* __restrict__ sn_tab) {
    int idx = blockIdx.x * 256 + threadIdx.x;  // 2*4*2048*16 = 262144
    int j4 = idx & 15;
    int s = (idx >> 4) & 2047;
    int r = idx >> 15;        // b*4 + hh
    int hh = r & 3, b = r >> 2;
    int p = pos[b * S_LEN + s];
    float4 cs = cs_tab[p * 16 + j4];
    float4 sn = sn_tab[p * 16 + j4];
    u16* base = Kb + (((size_t)(b * NKV + hh)) * S_LEN + s) * DHEAD + j4 * 4;
    ushort4 a = *(const ushort4*)(base);
    ushort4 c = *(const ushort4*)(base + 64);
    ushort4 oa, oc;
    float x1, x2;
    x1 = bf2f(a.x); x2 = bf2f(c.x); oa.x = f2bf(x1 * cs.x - x2 * sn.x); oc.x = f2bf(x2 * cs.x + x1 * sn.x);
    x1 = bf2f(a.y); x2 = bf2f(c.y); oa.y = f2bf(x1 * cs.y - x2 * sn.y); oc.y = f2bf(x2 * cs.y + x1 * sn.y);
    x1 = bf2f(a.z); x2 = bf2f(c.z); oa.z = f2bf(x1 * cs.z - x2 * sn.z); oc.z = f2bf(x2 * cs.z + x1 * sn.z);
    x1 = bf2f(a.w); x2 = bf2f(c.w); oa.w = f2bf(x1 * cs.w - x2 * sn.w); oc.w = f2bf(x2 * cs.w + x1 * sn.w);
    *(ushort4*)(base) = oa;
    *(ushort4*)(base + 64) = oc;
}

// ---------------- shared GEMM mainloop: A[M][K] bf16, Bt[N][K] bf16, 128x128 tile ----------------
// BK=64: LDS 128 rows x 64 u16 per matrix (16 KB each), 8 chunks of 8 u16 per
// row; chunk slot c holds global chunk c ^ (row&7) -> conflict-free ds_read_b128.
__device__ __forceinline__ void gemm_mainloop(const u16* __restrict__ A,
                                              const u16* __restrict__ Bt,
                                              int K, u16* ldsA, u16* ldsB,
                                              floatx4 acc[4][4]) {
    const int t = threadIdx.x;
    const int lane = t & 63, wave = t >> 6;
    const int wr = wave >> 1, wc = wave & 1;
    const int lr = lane & 15, q = lane >> 4;
    const int m0 = blockIdx.y * 128, n0 = blockIdx.x * 128;
    const int swz = lr & 7;

#pragma unroll
    for (int r = 0; r < 4; ++r)
#pragma unroll
        for (int c = 0; c < 4; ++c) acc[r][c] = zf4();

    for (int k0 = 0; k0 < K; k0 += 64) {
#pragma unroll
        for (int i = 0; i < 4; ++i) {
            int ci = i * 256 + t;
            int row = ci >> 3;
            int kc = ((ci & 7) ^ (row & 7)) << 3;
            async16(A + (size_t)(m0 + row) * K + k0 + kc, ldsA + (i * 256 + wave * 64) * 8);
            async16(Bt + (size_t)(n0 + row) * K + k0 + kc, ldsB + (i * 256 + wave * 64) * 8);
        }
        __syncthreads();
#pragma unroll
        for (int ks = 0; ks < 2; ++ks) {
            short8 af[4], bfr[4];
#pragma unroll
            for (int r = 0; r < 4; ++r)
                af[r] = *(const short8*)(ldsA + (wr * 64 + r * 16 + lr) * 64 +
                                         (((ks * 4 + q) ^ swz) << 3));
#pragma unroll
            for (int c = 0; c < 4; ++c)
                bfr[c] = *(const short8*)(ldsB + (wc * 64 + c * 16 + lr) * 64 +
                                          (((ks * 4 + q) ^ swz) << 3));
#pragma unroll
            for (int r = 0; r < 4; ++r)
#pragma unroll
                for (int c = 0; c < 4; ++c)
                    acc[r][c] = mfma16(af[r], bfr[c], acc[r][c]);
        }
        __syncthreads();
    }
}

// ---------------- QKV GEMM: scatter epilogue into Q/K/V^T bf16 ----------------
// V^T is stored with the two 4-key halves of each 8-key chunk swapped for dims
// with bit3 set (s ^ 4 when d&8): lets fa's b64 V reads spread across all 32
// banks (the staging copy is verbatim, so the swap must live in global layout).
__global__ void qkv_gemm_kernel(const u16* __restrict__ A, const u16* __restrict__ Bt,
                                u16* __restrict__ Qb, u16* __restrict__ Kb,
                                u16* __restrict__ Vt) {
    __shared__ u16 ldsA[128 * 64];
    __shared__ u16 ldsB[128 * 64];
    floatx4 acc[4][4];
    gemm_mainloop(A, Bt, D_MODEL, ldsA, ldsB, acc);

    const int t = threadIdx.x, lane = t & 63, wave = t >> 6;
    const int wr = wave >> 1, wc = wave & 1, lr = lane & 15, q = lane >> 4;
    const int m0 = blockIdx.y * 128 + wr * 64, n0 = blockIdx.x * 128 + wc * 64;
#pragma unroll
    for (int r = 0; r < 4; ++r)
#pragma unroll
        for (int c = 0; c < 4; ++c) {
            int gc = n0 + c * 16 + lr;
#pragma unroll
            for (int rr = 0; rr < 4; ++rr) {
                int grow = m0 + r * 16 + q * 4 + rr;  // token
                int bb = grow >> 11, s = grow & 2047;
                u16 bv = f2bf(acc[r][c][rr]);
                int d = gc & 127;
                if (gc < 2048) {
                    int hh = gc >> 7;
                    Qb[(((size_t)(bb * NH + hh)) * S_LEN + s) * DHEAD + d] = bv;
                } else if (gc < 2560) {
                    int hh = (gc - 2048) >> 7;
                    Kb[(((size_t)(bb * NKV + hh)) * S_LEN + s) * DHEAD + d] = bv;
                } else {
                    int hh = (gc - 2560) >> 7;
                    int s2 = s ^ ((d & 8) >> 1);  // V half-spread (see header comment)
                    Vt[(((size_t)(bb * NKV + hh)) * DHEAD + d) * S_LEN + s2] = bv;
                }
            }
        }
}

// ---------------- out GEMM: fp32 epilogue to d_out ----------------
__global__ void out_gemm_kernel(const u16* __restrict__ A, const u16* __restrict__ Bt,
                                float* __restrict__ out) {
    __shared__ u16 ldsA[128 * 64];
    __shared__ u16 ldsB[128 * 64];
    floatx4 acc[4][4];
    gemm_mainloop(A, Bt, D_MODEL, ldsA, ldsB, acc);

    const int t = threadIdx.x, lane = t & 63, wave = t >> 6;
    const int wr = wave >> 1, wc = wave & 1, lr = lane & 15, q = lane >> 4;
    const int m0 = blockIdx.y * 128 + wr * 64, n0 = blockIdx.x * 128 + wc * 64;
#pragma unroll
    for (int r = 0; r < 4; ++r)
#pragma unroll
        for (int c = 0; c < 4; ++c) {
            int gc = n0 + c * 16 + lr;
#pragma unroll
            for (int rr = 0; rr < 4; ++rr) {
                int grow = m0 + r * 16 + q * 4 + rr;
                out[(size_t)grow * D_MODEL + gc] = acc[r][c][rr];
            }
        }
}

// ---------------- flash attention: dual-segment, counted-vmcnt pipeline ----------------
// Grid 512: bid -> (bh = bid>>4, p = bid&15).  Each block owns TWO query tiles
// qt0=p and qt1=31-p and processes them IN THE SAME K-LOOP: seg0's k-tiles are a
// subset of seg1's (qt0 < qt1), so one staged K/V tile feeds BOTH segments.
// One K-fragment ds_read -> two MFMAs; staged volume drops 528->392 tiles/bh
// (-26%) and the compute:staging ratio doubles on the shared range.
// T4 counted vmcnt (m218 +38-73%): stage(t+1)=8 loads/thread, then
// s_waitcnt vmcnt(8) waits only tile-t's 8 oldest; raw s_barrier (no vmcnt(0)
// drain -> t+1 deliveries pipeline across barriers).  Post-compute raw barrier
// needs no drain: every ds_read retires before its consuming MFMA (compiler
// lgkmcnt), so all reads of buf[cur] are done when a wave reaches it.
// QK^T: S^T = K.Q^T via 16x16x32 -> C-layout (query=lane&15, key=quad*4+reg).
// PV: O^T += V^T.P^T via 16x16x16; V b64 reads use the half-spread layout.
// RoPE on Q fused (identical f2bf math to the old rope pass -> bit-identical).
__global__ __launch_bounds__(256, 2) void fa_kernel(const u16* __restrict__ Qb,
                                                    const u16* __restrict__ Kb,
                                                    const u16* __restrict__ Vt,
                                                    u16* __restrict__ Ob,
                                                    const int* __restrict__ pos,
                                                    const float4* __restrict__ cs_tab,
                                                    const float4* __restrict__ sn_tab) {
    __shared__ u16 ldsK[2][64 * 128];
    __shared__ u16 ldsV[2][128 * 64];

    const int t = threadIdx.x, lane = t & 63, wave = t >> 6;
    const int lr = lane & 15, q = lane >> 4;
    const int swz = lr & 7;

    const int bid = blockIdx.x;
    const int bh = bid >> 4, p = bid & 15;
    const int qt0 = p, qt1 = 31 - p;
    const int b = bh >> 4, h = bh & 15;
    const int kvh = h >> 2;

    const u16* Kp = Kb + (size_t)(b * NKV + kvh) * S_LEN * DHEAD;
    const u16* Vp = Vt + (size_t)(b * NKV + kvh) * DHEAD * S_LEN;

    // Q fragments for both segments, RoPE'd in registers.
    // B-operand: n = lane&15 = query, k = quad*8+j; pair (d, d+64) = (qf[kk], qf[kk+2])
    short8 qf0[4], qf1[4];
    auto load_rope_q = [&](int qt, short8 (&qf)[4]) {
        const u16* Qp = Qb + ((size_t)((b * NH + h) * S_LEN) + qt * 64 + wave * 16) * DHEAD;
#pragma unroll
        for (int kk = 0; kk < 4; ++kk)
            qf[kk] = *(const short8*)(Qp + (size_t)lr * DHEAD + kk * 32 + q * 8);
        const int srow = qt * 64 + wave * 16 + lr;
        const int pp = pos[b * S_LEN + srow];
#pragma unroll
        for (int kk = 0; kk < 2; ++kk)
#pragma unroll
            for (int h4 = 0; h4 < 2; ++h4) {
                float4 cs = cs_tab[pp * 16 + kk * 8 + q * 2 + h4];
                float4 sn = sn_tab[pp * 16 + kk * 8 + q * 2 + h4];
#pragma unroll
                for (int e = 0; e < 4; ++e) {
                    float cc = (&cs.x)[e], ss = (&sn.x)[e];
                    int ei = h4 * 4 + e;
                    float x1 = bf2f((u16)qf[kk][ei]);
                    float x2 = bf2f((u16)qf[kk + 2][ei]);
                    qf[kk][ei]     = (short)f2bf(x1 * cc - x2 * ss);
                    qf[kk + 2][ei] = (short)f2bf(x2 * cc + x1 * ss);
                }
            }
    };
    load_rope_q(qt0, qf0);
    load_rope_q(qt1, qf1);

    // issue 8 global_load_lds (4 K + 4 V per thread) for k-tile kt into buffer bs
    auto stage = [&](int kt, int bs) {
#pragma unroll
        for (int i = 0; i < 4; ++i) {
            int ci = i * 256 + t;
            int krow = ci >> 4, kc = ((ci & 15) ^ ((ci >> 4) & 7)) << 3;
            async16(Kp + (size_t)(kt * 64 + krow) * DHEAD + kc,
                    &ldsK[bs][(i * 256 + wave * 64) * 8]);
            int dh = ci >> 3, vc = ((ci & 7) ^ ((ci >> 3) & 7)) << 3;
            async16(Vp + (size_t)dh * S_LEN + kt * 64 + vc,
                    &ldsV[bs][(i * 256 + wave * 64) * 8]);
        }
    };

    floatx4 accO0[8], accO1[8];  // O^T: (query=lane&15, d = dblk*16 + quad*4 + reg)
#pragma unroll
    for (int d = 0; d < 8; ++d) { accO0[d] = zf4(); accO1[d] = zf4(); }
    float m0v = -3e38f, l0v = 0.f, m1v = -3e38f, l1v = 0.f;

    // causal mask on the diagonal tile: key > query -> -inf (tile-local indices)
    auto do_mask = [&](floatx4 (&sc)[4]) {
        const int qrow = wave * 16 + lr;
#pragma unroll
        for (int c = 0; c < 4; ++c)
#pragma unroll
            for (int rr = 0; rr < 4; ++rr)
                if (c * 16 + q * 4 + rr > qrow) sc[c][rr] = -3e38f;
    };

    // online softmax + pack P^T fragment (B-operand of 16x16x16: n=query, k=quad*4+j)
    auto softmax_pack = [&](floatx4 (&sc)[4], float& m_i, float& l_i,
                            floatx4 (&accO)[8], short4v (&pb)[4]) {
        float mx = -3e38f;
#pragma unroll
        for (int c = 0; c < 4; ++c)
#pragma unroll
            for (int rr = 0; rr < 4; ++rr) mx = fmaxf(mx, sc[c][rr]);
        mx = fmaxf(mx, __shfl_xor(mx, 16));
        mx = fmaxf(mx, __shfl_xor(mx, 32));
        float mnew = fmaxf(m_i, mx);
        float mk = mnew * K2;
        bool anyup = __any(mnew > m_i);
        float rs = 0.f;
#pragma unroll
        for (int c = 0; c < 4; ++c)
#pragma unroll
            for (int rr = 0; rr < 4; ++rr) {
                float pe = __builtin_amdgcn_exp2f(fmaf(sc[c][rr], K2, -mk));
                sc[c][rr] = pe;
                rs += pe;
            }
        rs += __shfl_xor(rs, 16);
        rs += __shfl_xor(rs, 32);
        if (anyup) {  // whole-wave skip: most k-tiles leave the running max unchanged
            float alpha = __builtin_amdgcn_exp2f(fmaf(m_i, K2, -mk));
            l_i = l_i * alpha + rs;
#pragma unroll
            for (int d = 0; d < 8; ++d) accO[d] *= alpha;
        } else {
            l_i += rs;
        }
        m_i = mnew;
#pragma unroll
        for (int c = 0; c < 4; ++c) {
            pb[c][0] = (short)f2bfr(sc[c][0]);
            pb[c][1] = (short)f2bfr(sc[c][1]);
            pb[c][2] = (short)f2bfr(sc[c][2]);
            pb[c][3] = (short)f2bfr(sc[c][3]);
        }
    };

    // clean vmcnt slate (qf/pos loads) so the counted waits below are exact
    asm volatile("s_waitcnt vmcnt(0)" ::: "memory");
    stage(0, 0);
    int cur = 0;

    for (int kt = 0; kt <= qt1; ++kt) {
        stage(kt < qt1 ? kt + 1 : 0, cur ^ 1);  // dummy re-stage on last iter keeps counts uniform
        asm volatile("s_waitcnt vmcnt(8)" ::: "memory");  // tile kt landed; t+1 stays in flight
        __builtin_amdgcn_s_barrier();

        const bool act0 = (kt <= qt0);
        floatx4 sc0[4], sc1[4];

        // S^T: one kfr ds_read feeds both segments' MFMAs
        __builtin_amdgcn_s_setprio(1);
        if (act0) {
#pragma unroll
            for (int c = 0; c < 4; ++c) {
                sc0[c] = zf4(); sc1[c] = zf4();
#pragma unroll
                for (int kk = 0; kk < 4; ++kk) {
                    short8 kfr = *(const short8*)(&ldsK[cur][(c * 16 + lr) * DHEAD +
                                                  (((kk * 4 + q) ^ swz) << 3)]);
                    sc1[c] = mfma16(kfr, qf1[kk], sc1[c]);
                    sc0[c] = mfma16(kfr, qf0[kk], sc0[c]);
                }
            }
        } else {
#pragma unroll
            for (int c = 0; c < 4; ++c) {
                sc1[c] = zf4();
#pragma unroll
                for (int kk = 0; kk < 4; ++kk) {
                    short8 kfr = *(const short8*)(&ldsK[cur][(c * 16 + lr) * DHEAD +
                                                  (((kk * 4 + q) ^ swz) << 3)]);
                    sc1[c] = mfma16(kfr, qf1[kk], sc1[c]);
                }
            }
        }
        __builtin_amdgcn_s_setprio(0);

        if (kt == qt0) do_mask(sc0);
        if (kt == qt1) do_mask(sc1);

        short4v pb0[4], pb1[4];
        softmax_pack(sc1, m1v, l1v, accO1, pb1);
        if (act0) softmax_pack(sc0, m0v, l0v, accO0, pb0);

        // PV: one vf ds_read feeds both segments' MFMAs
        __builtin_amdgcn_s_setprio(1);
        if (act0) {
#pragma unroll
            for (int ks = 0; ks < 4; ++ks)
#pragma unroll
                for (int d = 0; d < 8; ++d) {
                    short4v vf = *(const short4v*)(&ldsV[cur][(d * 16 + lr) * 64 +
                                                   (((ks * 2 + (q >> 1)) ^ swz) << 3) +
                                                   (((q ^ (lr >> 3)) & 1) << 2)]);
                    accO1[d] = mfma16k16(vf, pb1[ks], accO1[d]);
                    accO0[d] = mfma16k16(vf, pb0[ks], accO0[d]);
                }
        } else {
#pragma unroll
            for (int ks = 0; ks < 4; ++ks)
#pragma unroll
                for (int d = 0; d < 8; ++d) {
                    short4v vf = *(const short4v*)(&ldsV[cur][(d * 16 + lr) * 64 +
                                                   (((ks * 2 + (q >> 1)) ^ swz) << 3) +
                                                   (((q ^ (lr >> 3)) & 1) << 2)]);
                    accO1[d] = mfma16k16(vf, pb1[ks], accO1[d]);
                }
        }
        __builtin_amdgcn_s_setprio(0);

        __builtin_amdgcn_s_barrier();  // all waves done reading buf[cur] (no drain needed)
        cur ^= 1;
    }

    // epilogue: O^T / l -> Ob [token][h*128 + d]; d contiguous per lane -> ushort4
    auto epilogue = [&](int qt_c, floatx4 (&accO)[8], float l_i) {
        const int tok = qt_c * 64 + wave * 16 + lr;
        const float inv = 1.0f / l_i;
        u16* orow = Ob + ((size_t)(b * S_LEN + tok)) * (NH * DHEAD) + h * DHEAD + q * 4;
#pragma unroll
        for (int d = 0; d < 8; ++d) {
            ushort4 o;
            o.x = f2bf(accO[d][0] * inv);
            o.y = f2bf(accO[d][1] * inv);
            o.z = f2bf(accO[d][2] * inv);
            o.w = f2bf(accO[d][3] * inv);
            *(ushort4*)(orow + d * 16) = o;
        }
    };
    epilogue(qt0, accO0, l0v);
    epilogue(qt1, accO1, l1v);
    asm volatile("s_waitcnt vmcnt(0)" ::: "memory");  // dummy-staged loads land before exit
}

extern "C" void kernel_launch(void* const* d_in, const int* in_sizes, int n_in,
                              void* d_out, int out_size, void* d_ws, size_t ws_size,
                              hipStream_t stream) {
    const float* X  = (const float*)d_in[0];
    const int* pos  = (const int*)d_in[1];
    const float* wq = (const float*)d_in[2];
    const float* wk = (const float*)d_in[3];
    const float* wv = (const float*)d_in[4];
    const float* wo = (const float*)d_in[5];
    float* out = (float*)d_out;

    char* w = (char*)d_ws;
    u16* Xbf    = (u16*)(w);                    // 4096*2048*2      = 16777216
    u16* Wqkv   = (u16*)(w + 16777216);         // 3072*2048*2      = 12582912
    u16* Wo     = (u16*)(w + 29360128);         // 2048*2048*2      =  8388608
    u16* Qb     = (u16*)(w + 37748736);         // 2*16*2048*128*2  = 16777216
    u16* Kb     = (u16*)(w + 54525952);         // 2*4*2048*128*2   =  4194304
    u16* Vt     = (u16*)(w + 58720256);         //                  =  4194304
    u16* Ob     = (u16*)(w + 62914560);         // 4096*2048*2      = 16777216
    float* cst  = (float*)(w + 79691776);       // 2048*64*4        =   524288
    float* snt  = (float*)(w + 80216064);       //                  =   524288

    cast_tables_kernel<<<8704, 256, 0, stream>>>((const float4*)X, (ushort4*)Xbf, cst, snt);
    transpose_all_kernel<<<dim3(160, 64), 256, 0, stream>>>(wq, wk, wv, wo, Wqkv, Wo);
    qkv_gemm_kernel<<<dim3(24, 32), 256, 0, stream>>>(Xbf, Wqkv, Qb, Kb, Vt);
    rope_k_kernel<<<1024, 256, 0, stream>>>(Kb, pos, (const float4*)cst, (const float4*)snt);
    fa_kernel<<<512, 256, 0, stream>>>(Qb, Kb, Vt, Ob, pos, (const float4*)cst, (const float4*)snt);
    out_gemm_kernel<<<dim3(16, 32), 256, 0, stream>>>(Ob, Wo, out);
}

// Round 5
// 297.892 us; speedup vs baseline: 1.0866x; 1.0866x over previous
//
#include <hip/hip_runtime.h>
#include <cmath>

typedef unsigned short u16;
typedef float floatx4 __attribute__((ext_vector_type(4)));
typedef short short8 __attribute__((ext_vector_type(8)));
typedef short short4v __attribute__((ext_vector_type(4)));
typedef __bf16 bf16x8 __attribute__((ext_vector_type(8)));

#define GLOBAL_AS __attribute__((address_space(1)))
#define LDS_AS __attribute__((address_space(3)))

#define S_LEN 2048
#define D_MODEL 2048
#define NH 16
#define NKV 4
#define DHEAD 128
#define SM_SCALE 0.08838834764831843f
#define K2 (SM_SCALE * 1.4426950408889634f) /* SM_SCALE * log2(e) */

__device__ __forceinline__ u16 f2bf(float f) {
    unsigned int u = __builtin_bit_cast(unsigned int, f);
    u += 0x7fffu + ((u >> 16) & 1u);
    return (u16)(u >> 16);
}
// cheap round-to-nearest (no tie-to-even): 2 VALU ops, used in the fa inner loop
__device__ __forceinline__ u16 f2bfr(float f) {
    unsigned int u = __builtin_bit_cast(unsigned int, f);
    return (u16)((u + 0x8000u) >> 16);
}
__device__ __forceinline__ float bf2f(u16 x) {
    unsigned int u = ((unsigned int)x) << 16;
    return __builtin_bit_cast(float, u);
}
__device__ __forceinline__ floatx4 zf4() {
    floatx4 z; z[0] = 0.f; z[1] = 0.f; z[2] = 0.f; z[3] = 0.f; return z;
}
__device__ __forceinline__ floatx4 mfma16(short8 a, short8 b, floatx4 c) {
    return __builtin_amdgcn_mfma_f32_16x16x32_bf16(
        __builtin_bit_cast(bf16x8, a), __builtin_bit_cast(bf16x8, b), c, 0, 0, 0);
}
// K=16 MFMA: A/B = 4 bf16 (2 VGPRs), k = quad*4 + j
__device__ __forceinline__ floatx4 mfma16k16(short4v a, short4v b, floatx4 c) {
    return __builtin_amdgcn_mfma_f32_16x16x16bf16_1k(a, b, c, 0, 0, 0);
}
__device__ __forceinline__ void async16(const u16* g, u16* l) {
    __builtin_amdgcn_global_load_lds((GLOBAL_AS void*)g, (LDS_AS void*)l, 16, 0, 0);
}

// ---------------- cast X fp32 -> bf16, plus rope tables (fused: one launch) ----------------
__global__ void cast_tables_kernel(const float4* __restrict__ in, ushort4* __restrict__ out,
                                   float* __restrict__ cs_tab, float* __restrict__ sn_tab) {
    int bid = blockIdx.x;
    if (bid < 8192) {
        int i = bid * 256 + threadIdx.x;
        float4 v = in[i];
        ushort4 o;
        o.x = f2bf(v.x); o.y = f2bf(v.y); o.z = f2bf(v.z); o.w = f2bf(v.w);
        out[i] = o;
    } else {
        int idx = (bid - 8192) * 256 + threadIdx.x;  // 2048*64
        int p = idx >> 6, jj = idx & 63;
        double e = (double)(2 * jj) / 128.0;
        double invf = pow(10000.0, -e);
        float arg = (float)p * (float)invf;  // match reference's fp32 angle
        cs_tab[idx] = (float)cos((double)arg);
        sn_tab[idx] = (float)sin((double)arg);
    }
}

// ---------------- transpose + cast all 4 weights in one launch ----------------
// in[R=2048][C] fp32 -> out[C][R] bf16.  blockIdx.x ranges select the matrix.
__global__ void transpose_all_kernel(const float* __restrict__ wq, const float* __restrict__ wk,
                                     const float* __restrict__ wv, const float* __restrict__ wo,
                                     u16* __restrict__ Wqkv, u16* __restrict__ Wo) {
    __shared__ float tile[32][33];
    int x = blockIdx.x;
    const float* in; u16* out; int C, bx;
    if (x < 64)      { in = wq; out = Wqkv;                     C = 2048; bx = x * 32; }
    else if (x < 80) { in = wk; out = Wqkv + (size_t)2048*2048; C = 512;  bx = (x - 64) * 32; }
    else if (x < 96) { in = wv; out = Wqkv + (size_t)2560*2048; C = 512;  bx = (x - 80) * 32; }
    else             { in = wo; out = Wo;                       C = 2048; bx = (x - 96) * 32; }
    const int R = 2048;
    int tx = threadIdx.x & 31, ty = threadIdx.x >> 5;
    int by = blockIdx.y * 32;  // over R
#pragma unroll
    for (int i = 0; i < 32; i += 8)
        tile[ty + i][tx] = in[(size_t)(by + ty + i) * C + bx + tx];
    __syncthreads();
#pragma unroll
    for (int i = 0; i < 32; i += 8)
        out[(size_t)(bx + ty + i) * R + by + tx] = f2bf(tile[tx][ty + i]);
}

// ---------------- apply RoPE in place on K only (Q rope is fused into fa) ----------------
__global__ void rope_k_kernel(u16* __restrict__ Kb, const int* __restrict__ pos,
                              const float4* __restrict__ cs_tab,
                              const float4* __restrict__ sn_tab) {
    int idx = blockIdx.x * 256 + threadIdx.x;  // 2*4*2048*16 = 262144
    int j4 = idx & 15;
    int s = (idx >> 4) & 2047;
    int r = idx >> 15;        // b*4 + hh
    int hh = r & 3, b = r >> 2;
    int p = pos[b * S_LEN + s];
    float4 cs = cs_tab[p * 16 + j4];
    float4 sn = sn_tab[p * 16 + j4];
    u16* base = Kb + (((size_t)(b * NKV + hh)) * S_LEN + s) * DHEAD + j4 * 4;
    ushort4 a = *(const ushort4*)(base);
    ushort4 c = *(const ushort4*)(base + 64);
    ushort4 oa, oc;
    float x1, x2;
    x1 = bf2f(a.x); x2 = bf2f(c.x); oa.x = f2bf(x1 * cs.x - x2 * sn.x); oc.x = f2bf(x2 * cs.x + x1 * sn.x);
    x1 = bf2f(a.y); x2 = bf2f(c.y); oa.y = f2bf(x1 * cs.y - x2 * sn.y); oc.y = f2bf(x2 * cs.y + x1 * sn.y);
    x1 = bf2f(a.z); x2 = bf2f(c.z); oa.z = f2bf(x1 * cs.z - x2 * sn.z); oc.z = f2bf(x2 * cs.z + x1 * sn.z);
    x1 = bf2f(a.w); x2 = bf2f(c.w); oa.w = f2bf(x1 * cs.w - x2 * sn.w); oc.w = f2bf(x2 * cs.w + x1 * sn.w);
    *(ushort4*)(base) = oa;
    *(ushort4*)(base + 64) = oc;
}

// ---------------- shared GEMM mainloop: A[M][K] bf16, Bt[N][K] bf16, 128x128 tile ----------------
// BK=64: LDS 128 rows x 64 u16 per matrix (16 KB each), 8 chunks of 8 u16 per
// row; chunk slot c holds global chunk c ^ (row&7) -> conflict-free ds_read_b128.
__device__ __forceinline__ void gemm_mainloop(const u16* __restrict__ A,
                                              const u16* __restrict__ Bt,
                                              int K, u16* ldsA, u16* ldsB,
                                              floatx4 acc[4][4]) {
    const int t = threadIdx.x;
    const int lane = t & 63, wave = t >> 6;
    const int wr = wave >> 1, wc = wave & 1;
    const int lr = lane & 15, q = lane >> 4;
    const int m0 = blockIdx.y * 128, n0 = blockIdx.x * 128;
    const int swz = lr & 7;

#pragma unroll
    for (int r = 0; r < 4; ++r)
#pragma unroll
        for (int c = 0; c < 4; ++c) acc[r][c] = zf4();

    for (int k0 = 0; k0 < K; k0 += 64) {
#pragma unroll
        for (int i = 0; i < 4; ++i) {
            int ci = i * 256 + t;
            int row = ci >> 3;
            int kc = ((ci & 7) ^ (row & 7)) << 3;
            async16(A + (size_t)(m0 + row) * K + k0 + kc, ldsA + (i * 256 + wave * 64) * 8);
            async16(Bt + (size_t)(n0 + row) * K + k0 + kc, ldsB + (i * 256 + wave * 64) * 8);
        }
        __syncthreads();
#pragma unroll
        for (int ks = 0; ks < 2; ++ks) {
            short8 af[4], bfr[4];
#pragma unroll
            for (int r = 0; r < 4; ++r)
                af[r] = *(const short8*)(ldsA + (wr * 64 + r * 16 + lr) * 64 +
                                         (((ks * 4 + q) ^ swz) << 3));
#pragma unroll
            for (int c = 0; c < 4; ++c)
                bfr[c] = *(const short8*)(ldsB + (wc * 64 + c * 16 + lr) * 64 +
                                          (((ks * 4 + q) ^ swz) << 3));
#pragma unroll
            for (int r = 0; r < 4; ++r)
#pragma unroll
                for (int c = 0; c < 4; ++c)
                    acc[r][c] = mfma16(af[r], bfr[c], acc[r][c]);
        }
        __syncthreads();
    }
}

// ---------------- QKV GEMM: scatter epilogue into Q/K/V^T bf16 ----------------
// V^T is stored with the two 4-key halves of each 8-key chunk swapped for dims
// with bit3 set (s ^ 4 when d&8): lets fa's b64 V reads spread across all 32
// banks (the staging copy is verbatim, so the swap must live in global layout).
__global__ void qkv_gemm_kernel(const u16* __restrict__ A, const u16* __restrict__ Bt,
                                u16* __restrict__ Qb, u16* __restrict__ Kb,
                                u16* __restrict__ Vt) {
    __shared__ u16 ldsA[128 * 64];
    __shared__ u16 ldsB[128 * 64];
    floatx4 acc[4][4];
    gemm_mainloop(A, Bt, D_MODEL, ldsA, ldsB, acc);

    const int t = threadIdx.x, lane = t & 63, wave = t >> 6;
    const int wr = wave >> 1, wc = wave & 1, lr = lane & 15, q = lane >> 4;
    const int m0 = blockIdx.y * 128 + wr * 64, n0 = blockIdx.x * 128 + wc * 64;
#pragma unroll
    for (int r = 0; r < 4; ++r)
#pragma unroll
        for (int c = 0; c < 4; ++c) {
            int gc = n0 + c * 16 + lr;
#pragma unroll
            for (int rr = 0; rr < 4; ++rr) {
                int grow = m0 + r * 16 + q * 4 + rr;  // token
                int bb = grow >> 11, s = grow & 2047;
                u16 bv = f2bf(acc[r][c][rr]);
                int d = gc & 127;
                if (gc < 2048) {
                    int hh = gc >> 7;
                    Qb[(((size_t)(bb * NH + hh)) * S_LEN + s) * DHEAD + d] = bv;
                } else if (gc < 2560) {
                    int hh = (gc - 2048) >> 7;
                    Kb[(((size_t)(bb * NKV + hh)) * S_LEN + s) * DHEAD + d] = bv;
                } else {
                    int hh = (gc - 2560) >> 7;
                    int s2 = s ^ ((d & 8) >> 1);  // V half-spread (see header comment)
                    Vt[(((size_t)(bb * NKV + hh)) * DHEAD + d) * S_LEN + s2] = bv;
                }
            }
        }
}

// ---------------- out GEMM: fp32 epilogue to d_out ----------------
__global__ void out_gemm_kernel(const u16* __restrict__ A, const u16* __restrict__ Bt,
                                float* __restrict__ out) {
    __shared__ u16 ldsA[128 * 64];
    __shared__ u16 ldsB[128 * 64];
    floatx4 acc[4][4];
    gemm_mainloop(A, Bt, D_MODEL, ldsA, ldsB, acc);

    const int t = threadIdx.x, lane = t & 63, wave = t >> 6;
    const int wr = wave >> 1, wc = wave & 1, lr = lane & 15, q = lane >> 4;
    const int m0 = blockIdx.y * 128 + wr * 64, n0 = blockIdx.x * 128 + wc * 64;
#pragma unroll
    for (int r = 0; r < 4; ++r)
#pragma unroll
        for (int c = 0; c < 4; ++c) {
            int gc = n0 + c * 16 + lr;
#pragma unroll
            for (int rr = 0; rr < 4; ++rr) {
                int grow = m0 + r * 16 + q * 4 + rr;
                out[(size_t)grow * D_MODEL + gc] = acc[r][c][rr];
            }
        }
}

// ---------------- flash attention: 8-wave KV-sharing, 128-query tile ----------------
// Grid 512 x 512 threads (8 waves).  bid -> bh = bid>>4 (b*16+h), jslot = bid&15;
// qt2 = (bh&16) ? 15-jslot : jslot  -> the two co-resident blocks per CU (bid,
// bid+256 under mod-256 placement) sum to a uniform 34 k-tiles (makespan flat).
// Each block owns ONE 128-query tile (wave w -> queries qt2*128 + w*16 ..+15);
// one staged 64-key K/V tile feeds 8 waves (2x the old 4) -> staged volume
// halves (16896 -> 8704 block-tiles) and occupancy doubles (16 waves/CU): the
// r1/r3 plateau (MfmaUtil 25%) was per-wave serialization with only 2 waves/
// SIMD to overlap; this gives 4.  Per-wave register state identical to r3
// (~104 VGPR, cap 128 via launch_bounds) -> no spill (r4 lesson: WRITE_SIZE
// is the spill tripwire).
// LDS double-buffered (64 KB); stage(t+1) issued before compute(t); the
// __syncthreads vmcnt-drain lands after ~500cy of compute -> latency hidden.
// QK^T: S^T = K.Q^T via 16x16x32 -> C-layout (query=lane&15, key=quad*4+reg).
// PV: O^T += V^T.P^T via 16x16x16; V b64 reads use the half-spread layout.
// RoPE on Q fused (identical f2bf math to the old rope pass -> bit-identical).
__global__ __launch_bounds__(512, 4) void fa_kernel(const u16* __restrict__ Qb,
                                                    const u16* __restrict__ Kb,
                                                    const u16* __restrict__ Vt,
                                                    u16* __restrict__ Ob,
                                                    const int* __restrict__ pos,
                                                    const float4* __restrict__ cs_tab,
                                                    const float4* __restrict__ sn_tab) {
    __shared__ u16 ldsK[2][64 * 128];
    __shared__ u16 ldsV[2][128 * 64];

    const int t = threadIdx.x, lane = t & 63, wave = t >> 6;  // wave 0..7
    const int lr = lane & 15, q = lane >> 4;
    const int swz = lr & 7;

    const int bid = blockIdx.x;
    const int bh = bid >> 4, jslot = bid & 15;
    const int qt2 = (bh & 16) ? (15 - jslot) : jslot;   // pairs blocks to 34 tiles
    const int b = bh >> 4, h = bh & 15;
    const int kvh = h >> 2;

    const u16* Kp = Kb + (size_t)(b * NKV + kvh) * S_LEN * DHEAD;
    const u16* Vp = Vt + (size_t)(b * NKV + kvh) * DHEAD * S_LEN;
    const u16* Qp = Qb + ((size_t)((b * NH + h) * S_LEN) + qt2 * 128 + wave * 16) * DHEAD;

    short8 qf[4];  // B-operand: n = lane&15 = query, k = quad*8+j
#pragma unroll
    for (int kk = 0; kk < 4; ++kk)
        qf[kk] = *(const short8*)(Qp + (size_t)lr * DHEAD + kk * 32 + q * 8);

    // fused RoPE on Q: lane holds dims kk*32 + q*8 + e; pair (d, d+64) = (qf[kk], qf[kk+2])
    {
        const int srow = qt2 * 128 + wave * 16 + lr;
        const int pp = pos[b * S_LEN + srow];
#pragma unroll
        for (int kk = 0; kk < 2; ++kk)
#pragma unroll
            for (int h4 = 0; h4 < 2; ++h4) {
                float4 cs = cs_tab[pp * 16 + kk * 8 + q * 2 + h4];
                float4 sn = sn_tab[pp * 16 + kk * 8 + q * 2 + h4];
#pragma unroll
                for (int e = 0; e < 4; ++e) {
                    float cc = (&cs.x)[e], ss = (&sn.x)[e];
                    int ei = h4 * 4 + e;
                    float x1 = bf2f((u16)qf[kk][ei]);
                    float x2 = bf2f((u16)qf[kk + 2][ei]);
                    qf[kk][ei]     = (short)f2bf(x1 * cc - x2 * ss);
                    qf[kk + 2][ei] = (short)f2bf(x2 * cc + x1 * ss);
                }
            }
    }

    // issue 4 global_load_lds (2 K + 2 V per thread) for k-tile kt into buffer bs
    auto stage = [&](int kt, int bs) {
#pragma unroll
        for (int i = 0; i < 2; ++i) {
            int ci = i * 512 + t;                       // 0..1023 chunk id
            int krow = ci >> 4, kc = ((ci & 15) ^ (krow & 7)) << 3;
            async16(Kp + (size_t)(kt * 64 + krow) * DHEAD + kc,
                    &ldsK[bs][(i * 512 + wave * 64) * 8]);
            int dh = ci >> 3, vc = ((ci & 7) ^ (dh & 7)) << 3;
            async16(Vp + (size_t)dh * S_LEN + kt * 64 + vc,
                    &ldsV[bs][(i * 512 + wave * 64) * 8]);
        }
    };

    floatx4 accO[8];  // O^T: (query=lane&15, d = dblk*16 + quad*4 + reg)
#pragma unroll
    for (int d = 0; d < 8; ++d) accO[d] = zf4();
    float m_i = -3e38f, l_i = 0.f;  // per-query scalars (query = wave*16+lr)

    const int nkt = 2 * qt2 + 2;
    int cur = 0;
    stage(0, 0);
    __syncthreads();

    for (int kt = 0; kt < nkt; ++kt) {
        if (kt + 1 < nkt) stage(kt + 1, cur ^ 1);

        // S^T: 64 keys (m, blocks c) x 16 queries (n) per wave
        floatx4 sc[4];
        __builtin_amdgcn_s_setprio(1);
#pragma unroll
        for (int c = 0; c < 4; ++c) {
            sc[c] = zf4();
#pragma unroll
            for (int kk = 0; kk < 4; ++kk) {
                short8 kfr = *(const short8*)(&ldsK[cur][(c * 16 + lr) * DHEAD +
                                              (((kk * 4 + q) ^ swz) << 3)]);
                sc[c] = mfma16(kfr, qf[kk], sc[c]);
            }
        }
        __builtin_amdgcn_s_setprio(0);

        // causal mask: the last two tiles straddle the diagonal of the 128-query tile
        if (kt >= 2 * qt2) {
            const int koff = (kt - 2 * qt2) << 6;
            const int gq = wave * 16 + lr;  // query within the 128-tile
#pragma unroll
            for (int c = 0; c < 4; ++c)
#pragma unroll
                for (int rr = 0; rr < 4; ++rr)
                    if (koff + c * 16 + q * 4 + rr > gq) sc[c][rr] = -3e38f;
        }

        // online softmax, per lane (query fixed; keys split across regs + quads)
        float mx = -3e38f;
#pragma unroll
        for (int c = 0; c < 4; ++c)
#pragma unroll
            for (int rr = 0; rr < 4; ++rr) mx = fmaxf(mx, sc[c][rr]);
        mx = fmaxf(mx, __shfl_xor(mx, 16));
        mx = fmaxf(mx, __shfl_xor(mx, 32));
        float mnew = fmaxf(m_i, mx);
        float mk = mnew * K2;
        bool anyup = __any(mnew > m_i);
        float rs = 0.f;
#pragma unroll
        for (int c = 0; c < 4; ++c)
#pragma unroll
            for (int rr = 0; rr < 4; ++rr) {
                float pe = __builtin_amdgcn_exp2f(fmaf(sc[c][rr], K2, -mk));
                sc[c][rr] = pe;
                rs += pe;
            }
        rs += __shfl_xor(rs, 16);
        rs += __shfl_xor(rs, 32);
        if (anyup) {  // whole-wave skip: most k-tiles leave the running max unchanged
            float alpha = __builtin_amdgcn_exp2f(fmaf(m_i, K2, -mk));
            l_i = l_i * alpha + rs;
#pragma unroll
            for (int d = 0; d < 8; ++d) accO[d] *= alpha;
        } else {
            l_i += rs;
        }
        m_i = mnew;

        // pack P^T fragments: B-operand of 16x16x16 (n=query=lane&15, k=quad*4+j)
        short4v pb[4];
#pragma unroll
        for (int c = 0; c < 4; ++c) {
            pb[c][0] = (short)f2bfr(sc[c][0]);
            pb[c][1] = (short)f2bfr(sc[c][1]);
            pb[c][2] = (short)f2bfr(sc[c][2]);
            pb[c][3] = (short)f2bfr(sc[c][3]);
        }

        // PV: O^T(128 x 16) += V^T(128 x 64) . P^T(64 x 16), 16-key steps
        __builtin_amdgcn_s_setprio(1);
#pragma unroll
        for (int ks = 0; ks < 4; ++ks)
#pragma unroll
            for (int d = 0; d < 8; ++d) {
                short4v vf = *(const short4v*)(&ldsV[cur][(d * 16 + lr) * 64 +
                                               (((ks * 2 + (q >> 1)) ^ swz) << 3) +
                                               (((q ^ (lr >> 3)) & 1) << 2)]);
                accO[d] = mfma16k16(vf, pb[ks], accO[d]);
            }
        __builtin_amdgcn_s_setprio(0);

        __syncthreads();  // drains vmcnt (t+1 staged under this tile's compute)
        cur ^= 1;
    }

    // epilogue: O^T / l -> Ob [token][h*128 + d]; d contiguous per lane -> ushort4
    const int tok = qt2 * 128 + wave * 16 + lr;
    const float inv = 1.0f / l_i;
    u16* orow = Ob + ((size_t)(b * S_LEN + tok)) * (NH * DHEAD) + h * DHEAD + q * 4;
#pragma unroll
    for (int d = 0; d < 8; ++d) {
        ushort4 o;
        o.x = f2bf(accO[d][0] * inv);
        o.y = f2bf(accO[d][1] * inv);
        o.z = f2bf(accO[d][2] * inv);
        o.w = f2bf(accO[d][3] * inv);
        *(ushort4*)(orow + d * 16) = o;
    }
}

extern "C" void kernel_launch(void* const* d_in, const int* in_sizes, int n_in,
                              void* d_out, int out_size, void* d_ws, size_t ws_size,
                              hipStream_t stream) {
    const float* X  = (const float*)d_in[0];
    const int* pos  = (const int*)d_in[1];
    const float* wq = (const float*)d_in[2];
    const float* wk = (const float*)d_in[3];
    const float* wv = (const float*)d_in[4];
    const float* wo = (const float*)d_in[5];
    float* out = (float*)d_out;

    char* w = (char*)d_ws;
    u16* Xbf    = (u16*)(w);                    // 4096*2048*2      = 16777216
    u16* Wqkv   = (u16*)(w + 16777216);         // 3072*2048*2      = 12582912
    u16* Wo     = (u16*)(w + 29360128);         // 2048*2048*2      =  8388608
    u16* Qb     = (u16*)(w + 37748736);         // 2*16*2048*128*2  = 16777216
    u16* Kb     = (u16*)(w + 54525952);         // 2*4*2048*128*2   =  4194304
    u16* Vt     = (u16*)(w + 58720256);         //                  =  4194304
    u16* Ob     = (u16*)(w + 62914560);         // 4096*2048*2      = 16777216
    float* cst  = (float*)(w + 79691776);       // 2048*64*4        =   524288
    float* snt  = (float*)(w + 80216064);       //                  =   524288

    cast_tables_kernel<<<8704, 256, 0, stream>>>((const float4*)X, (ushort4*)Xbf, cst, snt);
    transpose_all_kernel<<<dim3(160, 64), 256, 0, stream>>>(wq, wk, wv, wo, Wqkv, Wo);
    qkv_gemm_kernel<<<dim3(24, 32), 256, 0, stream>>>(Xbf, Wqkv, Qb, Kb, Vt);
    rope_k_kernel<<<1024, 256, 0, stream>>>(Kb, pos, (const float4*)cst, (const float4*)snt);
    fa_kernel<<<512, 512, 0, stream>>>(Qb, Kb, Vt, Ob, pos, (const float4*)cst, (const float4*)snt);
    out_gemm_kernel<<<dim3(16, 32), 256, 0, stream>>>(Ob, Wo, out);
}